// Round 1
// baseline (106.133 us; speedup 1.0000x reference)
//
#include <hip/hip_runtime.h>
#include <math.h>

// Gaussian upsampling (Non-Attentive Tacotron): B=32, S=256, T=2048, D=256 (f32).
// Round 1: correct f32 vector baseline.
//   phase 0: in-block scan of durations -> centers c[s], ir2[s]
//   phase 1: w-tile [BM=32][S=256] in LDS (one t-tile per block)
//   phase 1b: row sums (rotated index -> conflict-free) -> 1/w2 per t
//   phase 2: f32 GEMM out[t,d] = sum_s w[t,s]*enc[s,d]; epilogue: *1/w2 + PE

#define BM 32
#define BLOCK 256
#define S_FIX 256

__global__ __launch_bounds__(BLOCK) void gauss_up_f32(
    const float* __restrict__ enc,   // (B,S,D)
    const float* __restrict__ dur,   // (B,S)
    const float* __restrict__ rng,   // (B,S,1)
    float* __restrict__ out,         // (B,T,D)
    int T, int D, int ntiles)
{
    __shared__ float s_w[BM][S_FIX];     // 32 KB
    __shared__ float s_c[S_FIX];
    __shared__ float s_ir2[S_FIX];
    __shared__ float s_scan[S_FIX];
    __shared__ float s_part[8][BM];
    __shared__ float s_winv[BM];

    const int tid = threadIdx.x;
    const int b   = blockIdx.x / ntiles;
    const int t0  = (blockIdx.x % ntiles) * BM;

    // ---- phase 0: inclusive scan of durations (S == BLOCK == 256) ----
    float dv = dur[b * S_FIX + tid];
    s_scan[tid] = dv;
    __syncthreads();
    #pragma unroll
    for (int off = 1; off < S_FIX; off <<= 1) {
        float cur = s_scan[tid];
        float add = (tid >= off) ? s_scan[tid - off] : 0.0f;
        __syncthreads();
        s_scan[tid] = cur + add;
        __syncthreads();
    }
    {
        float e = s_scan[tid];
        float c = e - 0.5f * dv;
        float r = rng[b * S_FIX + tid];
        s_c[tid]   = c;
        s_ir2[tid] = 1.0f / (r * r);
    }
    __syncthreads();

    // ---- phase 1: w1 tile [BM][S] (thread = one s column) ----
    {
        float cc = s_c[tid];
        float ir = s_ir2[tid];
        #pragma unroll 4
        for (int tl = 0; tl < BM; ++tl) {
            float tt = (float)(t0 + tl);
            float df = tt - cc;
            s_w[tl][tid] = __expf(-ir * df * df);
        }
    }
    __syncthreads();

    // ---- phase 1b: row sums -> s_winv (rotated index: 2-way max, free) ----
    {
        const int t  = tid & 31;
        const int ch = tid >> 5;           // 8 chunks of 32
        float ps = 0.0f;
        #pragma unroll 8
        for (int j = 0; j < 32; ++j)
            ps += s_w[t][ch * 32 + ((j + t) & 31)];
        s_part[ch][t] = ps;
    }
    __syncthreads();
    if (tid < BM) {
        float w2 = s_part[0][tid] + s_part[1][tid] + s_part[2][tid] + s_part[3][tid]
                 + s_part[4][tid] + s_part[5][tid] + s_part[6][tid] + s_part[7][tid]
                 + 1e-20f;
        s_winv[tid] = 1.0f / w2;
    }
    __syncthreads();

    // ---- phase 2: GEMM. wave tg owns rows tg*8..tg*8+7; lane dq owns d-quad ----
    const int dq = tid & 63;
    const int tg = tid >> 6;
    float4 acc[8];
    #pragma unroll
    for (int i = 0; i < 8; ++i) acc[i] = make_float4(0.f, 0.f, 0.f, 0.f);

    const float* encb = enc + (size_t)b * S_FIX * D + (size_t)dq * 4;
    #pragma unroll 4
    for (int s = 0; s < S_FIX; ++s) {
        float4 ev = *(const float4*)(encb + (size_t)s * D);
        #pragma unroll
        for (int i = 0; i < 8; ++i) {
            float wv = s_w[tg * 8 + i][s];   // wave-uniform -> LDS broadcast
            acc[i].x = fmaf(wv, ev.x, acc[i].x);
            acc[i].y = fmaf(wv, ev.y, acc[i].y);
            acc[i].z = fmaf(wv, ev.z, acc[i].z);
            acc[i].w = fmaf(wv, ev.w, acc[i].w);
        }
    }

    // ---- epilogue: normalize + sinusoidal PE + store ----
    const float kf = -logf(10000.0f) / (float)D;
    const int d0 = dq * 4;
    const float f0 = __expf(kf * (float)(d0));       // freq for d0, d0+1
    const float f2 = __expf(kf * (float)(d0 + 2));   // freq for d0+2, d0+3
    float* outb = out + (size_t)b * T * D + (size_t)t0 * D + d0;
    #pragma unroll
    for (int i = 0; i < 8; ++i) {
        const int tl = tg * 8 + i;
        const float inv = s_winv[tl];
        const float tt = (float)(t0 + tl);
        const float a0 = tt * f0;
        const float a2 = tt * f2;
        float4 o;
        o.x = acc[i].x * inv + __sinf(a0);
        o.y = acc[i].y * inv + __cosf(a0);
        o.z = acc[i].z * inv + __sinf(a2);
        o.w = acc[i].w * inv + __cosf(a2);
        *(float4*)(outb + (size_t)tl * D) = o;
    }
}

extern "C" void kernel_launch(void* const* d_in, const int* in_sizes, int n_in,
                              void* d_out, int out_size, void* d_ws, size_t ws_size,
                              hipStream_t stream) {
    const float* enc = (const float*)d_in[0];
    const float* dur = (const float*)d_in[1];
    const float* rng = (const float*)d_in[2];
    float* out = (float*)d_out;

    const int S  = S_FIX;               // reference static shape
    const int BS = in_sizes[1];         // B*S
    const int B  = BS / S;              // 32
    const int D  = in_sizes[0] / BS;    // 256
    const int T  = out_size / (B * D);  // 2048
    const int ntiles = T / BM;          // 64

    hipLaunchKernelGGL(gauss_up_f32, dim3(B * ntiles), dim3(BLOCK), 0, stream,
                       enc, dur, rng, out, T, D, ntiles);
}

// Round 2
// 52.430 us; speedup vs baseline: 2.0243x; 2.0243x over previous
//
#include <hip/hip_runtime.h>
#include <math.h>

// Gaussian upsampling, round 2: bf16 MFMA GEMM (m97 pattern).
//   prepass : enc (B,S,D) f32 -> encT (B,D,S) bf16 in d_ws
//   main    : per block (b, 64 t-rows):
//     phase 0 : scan durations -> c[s], ir2[s]
//     phase 1 : w-tile [64][256] bf16 in LDS, XOR-swizzled (G4 fix)
//     phase 1b: w2 row sums from bf16 tile -> s_winv
//     phase 2 : mfma_f32_16x16x32_bf16, A=w (LDS), B=encT (global, B^T form)
//     epilogue: *1/w2 + sinusoidal PE, f32 stores

typedef short  bf16x8 __attribute__((ext_vector_type(8)));
typedef float  f32x4  __attribute__((ext_vector_type(4)));
typedef unsigned short u16x8 __attribute__((ext_vector_type(8)));

#define BLOCK 256
#define S_FIX 256
#define D_FIX 256
#define BM 64

static __device__ __forceinline__ unsigned short f2bf(float f) {
    union { float f; unsigned u; } v; v.f = f;
    unsigned r = v.u + 0x7FFFu + ((v.u >> 16) & 1u);   // RNE
    return (unsigned short)(r >> 16);
}

// ---------------- prepass: enc (B,S,D) f32 -> encT (B,D,S) bf16 ----------------
__global__ __launch_bounds__(256) void transpose_enc_bf16(
    const float* __restrict__ enc, unsigned short* __restrict__ encT)
{
    // thread -> (b, s-chunk of 8, d). reads: wave = 256B contiguous per j. 
    const int g  = blockIdx.x * 256 + threadIdx.x;
    const int d  = g & 255;
    const int sc = (g >> 8) & 31;
    const int b  = g >> 13;
    const int s0 = sc * 8;
    const float* p = enc + ((size_t)b << 16) + (size_t)s0 * D_FIX + d;
    u16x8 v;
    #pragma unroll
    for (int j = 0; j < 8; ++j) v[j] = f2bf(p[(size_t)j * D_FIX]);
    *(u16x8*)(encT + ((size_t)b << 16) + (size_t)d * S_FIX + s0) = v;
}

// ---------------- main MFMA kernel ----------------
__global__ __launch_bounds__(BLOCK, 4) void gauss_up_mfma(
    const float* __restrict__ dur,            // (B,S)
    const float* __restrict__ rng,            // (B,S,1)
    const unsigned short* __restrict__ encT,  // (B,D,S) bf16
    float* __restrict__ out,                  // (B,T,D)
    int T)
{
    __shared__ short s_w[BM * S_FIX];   // 32 KB bf16, row stride 512B, XOR-swizzled
    __shared__ float s_scan[S_FIX];
    __shared__ float s_c[S_FIX];
    __shared__ float s_ir2[S_FIX];
    __shared__ float s_part[4][BM];
    __shared__ float s_winv[BM];

    const int tid    = threadIdx.x;
    const int ntiles = T / BM;
    const int b      = blockIdx.x / ntiles;
    const int t0     = (blockIdx.x % ntiles) * BM;

    // ---- phase 0: inclusive scan of durations (s == tid) ----
    float dv = dur[b * S_FIX + tid];
    s_scan[tid] = dv;
    __syncthreads();
    #pragma unroll
    for (int off = 1; off < S_FIX; off <<= 1) {
        float cur = s_scan[tid];
        float add = (tid >= off) ? s_scan[tid - off] : 0.0f;
        __syncthreads();
        s_scan[tid] = cur + add;
        __syncthreads();
    }
    {
        float e = s_scan[tid];
        float r = rng[b * S_FIX + tid];
        s_c[tid]   = e - 0.5f * dv;
        s_ir2[tid] = 1.0f / (r * r);
    }
    __syncthreads();

    // ---- phase 1: w tile bf16 swizzled. thread = (s-pair, t-half); b32 writes ----
    {
        const int s2 = tid & 127;          // s = 2*s2, 2*s2+1
        const int th = tid >> 7;
        const float c0 = s_c[2 * s2],     i0 = s_ir2[2 * s2];
        const float c1 = s_c[2 * s2 + 1], i1 = s_ir2[2 * s2 + 1];
        char* base = (char*)s_w;
        #pragma unroll 4
        for (int tl = th * 32; tl < th * 32 + 32; ++tl) {
            float tt = (float)(t0 + tl);
            float e0 = tt - c0, e1 = tt - c1;
            float w0 = __expf(-i0 * e0 * e0);
            float w1 = __expf(-i1 * e1 * e1);
            unsigned pack = (unsigned)f2bf(w0) | ((unsigned)f2bf(w1) << 16);
            int byte = tl * 512 + ((4 * s2) ^ ((tl & 7) << 4));
            *(unsigned*)(base + byte) = pack;
        }
    }
    __syncthreads();

    // ---- phase 1b: w2[t] = sum_s bf16(w1); rotated reads ----
    {
        const int t  = tid & 63;
        const int ch = tid >> 6;
        const char* base = (const char*)s_w;
        float ps = 0.0f;
        #pragma unroll 8
        for (int j = 0; j < 64; ++j) {
            int s = ch * 64 + ((j + t) & 63);
            int byte = t * 512 + ((2 * s) ^ ((t & 7) << 4));
            unsigned short u = *(const unsigned short*)(base + byte);
            ps += __uint_as_float((unsigned)u << 16);
        }
        s_part[ch][t] = ps;
    }
    __syncthreads();
    if (tid < BM) {
        float w2 = s_part[0][tid] + s_part[1][tid] + s_part[2][tid] + s_part[3][tid] + 1e-20f;
        s_winv[tid] = 1.0f / w2;
    }
    __syncthreads();

    // ---- phase 2: MFMA GEMM. wave wid owns d-span [wid*64, wid*64+64) ----
    const int lane = tid & 63;
    const int wid  = tid >> 6;
    const int l15  = lane & 15;
    const int lg   = lane >> 4;     // k-group: k = k0 + lg*8 + j

    f32x4 acc[4][4];
    #pragma unroll
    for (int m = 0; m < 4; ++m)
        #pragma unroll
        for (int n = 0; n < 4; ++n) acc[m][n] = (f32x4){0.f, 0.f, 0.f, 0.f};

    const unsigned short* ebase =
        encT + ((size_t)b << 16) + (size_t)(wid * 64 + l15) * S_FIX + lg * 8;
    char* wbase = (char*)s_w;

    for (int k0 = 0; k0 < S_FIX; k0 += 32) {
        bf16x8 bfr[4];
        #pragma unroll
        for (int n = 0; n < 4; ++n)
            bfr[n] = *(const bf16x8*)(ebase + (size_t)n * 16 * S_FIX + k0);
        bf16x8 afr[4];
        #pragma unroll
        for (int m = 0; m < 4; ++m) {
            int tl = m * 16 + l15;
            int byte = tl * 512 + ((2 * (k0 + lg * 8)) ^ ((tl & 7) << 4));
            afr[m] = *(const bf16x8*)(wbase + byte);
        }
        #pragma unroll
        for (int m = 0; m < 4; ++m)
            #pragma unroll
            for (int n = 0; n < 4; ++n)
                acc[m][n] = __builtin_amdgcn_mfma_f32_16x16x32_bf16(
                    afr[m], bfr[n], acc[m][n], 0, 0, 0);
    }

    // ---- epilogue: normalize + sinusoidal PE + store ----
    const float kf = -logf(10000.0f) / (float)D_FIX;
    #pragma unroll
    for (int n = 0; n < 4; ++n) {
        const int d   = wid * 64 + n * 16 + l15;
        const float fr = __expf(kf * (float)(d & ~1));
        float* ob = out + (size_t)b * T * D_FIX + (size_t)t0 * D_FIX + d;
        #pragma unroll
        for (int m = 0; m < 4; ++m) {
            #pragma unroll
            for (int r = 0; r < 4; ++r) {
                const int tl = m * 16 + lg * 4 + r;       // C/D: row=(lane>>4)*4+reg
                const float a = (float)(t0 + tl) * fr;
                const float pe = (d & 1) ? __cosf(a) : __sinf(a);
                ob[(size_t)tl * D_FIX] = acc[m][n][r] * s_winv[tl] + pe;
            }
        }
    }
}

// ---------------- fallback (round-1 f32 kernel, used if ws too small) ----------------
#define FBM 32
__global__ __launch_bounds__(BLOCK) void gauss_up_f32(
    const float* __restrict__ enc, const float* __restrict__ dur,
    const float* __restrict__ rng, float* __restrict__ out,
    int T, int D, int ntiles)
{
    __shared__ float s_w[FBM][S_FIX];
    __shared__ float s_c[S_FIX];
    __shared__ float s_ir2[S_FIX];
    __shared__ float s_scan[S_FIX];
    __shared__ float s_part[8][FBM];
    __shared__ float s_winv[FBM];

    const int tid = threadIdx.x;
    const int b   = blockIdx.x / ntiles;
    const int t0  = (blockIdx.x % ntiles) * FBM;

    float dv = dur[b * S_FIX + tid];
    s_scan[tid] = dv;
    __syncthreads();
    #pragma unroll
    for (int off = 1; off < S_FIX; off <<= 1) {
        float cur = s_scan[tid];
        float add = (tid >= off) ? s_scan[tid - off] : 0.0f;
        __syncthreads();
        s_scan[tid] = cur + add;
        __syncthreads();
    }
    {
        float e = s_scan[tid];
        float c = e - 0.5f * dv;
        float r = rng[b * S_FIX + tid];
        s_c[tid] = c; s_ir2[tid] = 1.0f / (r * r);
    }
    __syncthreads();
    {
        float cc = s_c[tid], ir = s_ir2[tid];
        #pragma unroll 4
        for (int tl = 0; tl < FBM; ++tl) {
            float tt = (float)(t0 + tl);
            float df = tt - cc;
            s_w[tl][tid] = __expf(-ir * df * df);
        }
    }
    __syncthreads();
    {
        const int t = tid & 31, ch = tid >> 5;
        float ps = 0.0f;
        #pragma unroll 8
        for (int j = 0; j < 32; ++j) ps += s_w[t][ch * 32 + ((j + t) & 31)];
        s_part[ch][t] = ps;
    }
    __syncthreads();
    if (tid < FBM) {
        float w2 = s_part[0][tid] + s_part[1][tid] + s_part[2][tid] + s_part[3][tid]
                 + s_part[4][tid] + s_part[5][tid] + s_part[6][tid] + s_part[7][tid] + 1e-20f;
        s_winv[tid] = 1.0f / w2;
    }
    __syncthreads();

    const int dq = tid & 63, tg = tid >> 6;
    float4 acc[8];
    #pragma unroll
    for (int i = 0; i < 8; ++i) acc[i] = make_float4(0.f, 0.f, 0.f, 0.f);
    const float* encb = enc + (size_t)b * S_FIX * D + (size_t)dq * 4;
    #pragma unroll 4
    for (int s = 0; s < S_FIX; ++s) {
        float4 ev = *(const float4*)(encb + (size_t)s * D);
        #pragma unroll
        for (int i = 0; i < 8; ++i) {
            float wv = s_w[tg * 8 + i][s];
            acc[i].x = fmaf(wv, ev.x, acc[i].x);
            acc[i].y = fmaf(wv, ev.y, acc[i].y);
            acc[i].z = fmaf(wv, ev.z, acc[i].z);
            acc[i].w = fmaf(wv, ev.w, acc[i].w);
        }
    }
    const float kf = -logf(10000.0f) / (float)D;
    const int d0 = dq * 4;
    const float f0 = __expf(kf * (float)(d0));
    const float f2 = __expf(kf * (float)(d0 + 2));
    float* outb = out + (size_t)b * T * D + (size_t)t0 * D + d0;
    #pragma unroll
    for (int i = 0; i < 8; ++i) {
        const int tl = tg * 8 + i;
        const float inv = s_winv[tl];
        const float tt = (float)(t0 + tl);
        const float a0 = tt * f0, a2 = tt * f2;
        float4 o;
        o.x = acc[i].x * inv + __sinf(a0);
        o.y = acc[i].y * inv + __cosf(a0);
        o.z = acc[i].z * inv + __sinf(a2);
        o.w = acc[i].w * inv + __cosf(a2);
        *(float4*)(outb + (size_t)tl * D) = o;
    }
}

extern "C" void kernel_launch(void* const* d_in, const int* in_sizes, int n_in,
                              void* d_out, int out_size, void* d_ws, size_t ws_size,
                              hipStream_t stream) {
    const float* enc = (const float*)d_in[0];
    const float* dur = (const float*)d_in[1];
    const float* rng = (const float*)d_in[2];
    float* out = (float*)d_out;

    const int S  = S_FIX;
    const int BS = in_sizes[1];
    const int B  = BS / S;
    const int D  = in_sizes[0] / BS;
    const int T  = out_size / (B * D);

    const size_t need = (size_t)B * D * S * sizeof(unsigned short);  // 4 MB

    if (D == D_FIX && (T % BM) == 0 && ws_size >= need) {
        unsigned short* encT = (unsigned short*)d_ws;
        const int nthr = B * (S / 8) * D;                    // 262144
        hipLaunchKernelGGL(transpose_enc_bf16, dim3(nthr / 256), dim3(256), 0, stream,
                           enc, encT);
        hipLaunchKernelGGL(gauss_up_mfma, dim3(B * (T / BM)), dim3(BLOCK), 0, stream,
                           dur, rng, encT, out, T);
    } else {
        const int ntiles = T / FBM;
        hipLaunchKernelGGL(gauss_up_f32, dim3(B * ntiles), dim3(BLOCK), 0, stream,
                           enc, dur, rng, out, T, D, ntiles);
    }
}

// Round 3
// 49.270 us; speedup vs baseline: 2.1541x; 1.0641x over previous
//
#include <hip/hip_runtime.h>
#include <math.h>

// Gaussian upsampling, round 3: latency-bound fixes.
//   - BM=32, grid 2048 (8 blocks/CU), LDS union ~19.7 KB
//   - barrier-free shfl scan (1 barrier)
//   - phase 1b: b32 pair reads, rotated+swizzled (self-consistent bf16 sums)
//   - MFMA phase identical math to round 2 (validated layouts)
//   - epilogue: LDS transpose in 2 chunks -> coalesced dwordx4 row stores

typedef short  bf16x8 __attribute__((ext_vector_type(8)));
typedef float  f32x4  __attribute__((ext_vector_type(4)));
typedef unsigned short u16x8 __attribute__((ext_vector_type(8)));

#define BLOCK 256
#define S_FIX 256
#define D_FIX 256
#define BM 32
#define STG_STRIDE 258   // f32 staging row stride (spreads banks: 258 mod 32 = 2)

static __device__ __forceinline__ unsigned short f2bf(float f) {
    union { float f; unsigned u; } v; v.f = f;
    unsigned r = v.u + 0x7FFFu + ((v.u >> 16) & 1u);   // RNE
    return (unsigned short)(r >> 16);
}

// ---------------- prepass: enc (B,S,D) f32 -> encT (B,D,S) bf16 ----------------
__global__ __launch_bounds__(256) void transpose_enc_bf16(
    const float* __restrict__ enc, unsigned short* __restrict__ encT)
{
    const int g  = blockIdx.x * 256 + threadIdx.x;
    const int d  = g & 255;
    const int sc = (g >> 8) & 31;
    const int b  = g >> 13;
    const int s0 = sc * 8;
    const float* p = enc + ((size_t)b << 16) + (size_t)s0 * D_FIX + d;
    u16x8 v;
    #pragma unroll
    for (int j = 0; j < 8; ++j) v[j] = f2bf(p[(size_t)j * D_FIX]);
    *(u16x8*)(encT + ((size_t)b << 16) + (size_t)d * S_FIX + s0) = v;
}

// ---------------- main MFMA kernel ----------------
__global__ __launch_bounds__(BLOCK) void gauss_up_mfma(
    const float* __restrict__ dur,            // (B,S)
    const float* __restrict__ rng,            // (B,S,1)
    const unsigned short* __restrict__ encT,  // (B,D,S) bf16
    float* __restrict__ out,                  // (B,T,D)
    int T)
{
    // union: phase 1-2 = bf16 w-tile [32][256] (16384 B, XOR-swizzled)
    //        epilogue  = f32 staging [16][STG_STRIDE] (16512 B)
    __shared__ __align__(16) char smem[16 * STG_STRIDE * 4];
    __shared__ float s_c[S_FIX];
    __shared__ float s_ir2[S_FIX];
    __shared__ float s_part[8][BM];
    __shared__ float s_winv[BM];

    const int tid    = threadIdx.x;
    const int lane   = tid & 63;
    const int wid    = tid >> 6;
    const int ntiles = T / BM;
    const int b      = blockIdx.x / ntiles;
    const int t0     = (blockIdx.x % ntiles) * BM;

    // ---- phase 0: per-wave shfl scan (all 4 waves redundant; 1 barrier) ----
    {
        f32x4 dv = *(const f32x4*)(dur + b * S_FIX + 4 * lane);
        f32x4 rg = *(const f32x4*)(rng + b * S_FIX + 4 * lane);
        float q0 = dv[0];
        float q1 = q0 + dv[1];
        float q2 = q1 + dv[2];
        float q3 = q2 + dv[3];
        float tot = q3;
        #pragma unroll
        for (int off = 1; off < 64; off <<= 1) {
            float n = __shfl_up(tot, off, 64);
            if (lane >= off) tot += n;
        }
        float excl = __shfl_up(tot, 1, 64);
        if (lane == 0) excl = 0.0f;
        f32x4 c4, ir4;
        c4[0] = excl + q0 - 0.5f * dv[0];
        c4[1] = excl + q1 - 0.5f * dv[1];
        c4[2] = excl + q2 - 0.5f * dv[2];
        c4[3] = excl + q3 - 0.5f * dv[3];
        #pragma unroll
        for (int i = 0; i < 4; ++i) ir4[i] = 1.0f / (rg[i] * rg[i]);
        *(f32x4*)(s_c   + 4 * lane) = c4;
        *(f32x4*)(s_ir2 + 4 * lane) = ir4;
    }
    __syncthreads();

    // ---- phase 1: w tile bf16, XOR-swizzled; thread = (s-pair, t-half) ----
    {
        const int s2 = tid & 127;
        const int th = tid >> 7;
        const float c0 = s_c[2 * s2],     i0 = s_ir2[2 * s2];
        const float c1 = s_c[2 * s2 + 1], i1 = s_ir2[2 * s2 + 1];
        #pragma unroll
        for (int tl = th * 16; tl < th * 16 + 16; ++tl) {
            float tt = (float)(t0 + tl);
            float e0 = tt - c0, e1 = tt - c1;
            unsigned pack = (unsigned)f2bf(__expf(-i0 * e0 * e0))
                          | ((unsigned)f2bf(__expf(-i1 * e1 * e1)) << 16);
            int byte = tl * 512 + ((4 * s2) ^ ((tl & 7) << 4));
            *(unsigned*)(smem + byte) = pack;
        }
    }
    __syncthreads();

    // ---- phase 1b: w2[t] = sum_s bf16(w1), b32 pair reads, rotated ----
    {
        const int tl = tid & 31;
        const int ch = tid >> 5;            // 8 chunks x 16 pairs
        float ps = 0.0f;
        #pragma unroll
        for (int j = 0; j < 16; ++j) {
            int p = ch * 16 + ((j + tl) & 15);
            unsigned v = *(const unsigned*)(smem + tl * 512 + ((4 * p) ^ ((tl & 7) << 4)));
            ps += __uint_as_float(v << 16);
            ps += __uint_as_float(v & 0xFFFF0000u);
        }
        s_part[ch][tl] = ps;
    }
    __syncthreads();
    if (tid < BM) {
        float w2 = 1e-20f;
        #pragma unroll
        for (int ch = 0; ch < 8; ++ch) w2 += s_part[ch][tid];
        s_winv[tid] = 1.0f / w2;
    }
    __syncthreads();

    // ---- phase 2: MFMA. wave wid owns d-span [wid*64, wid*64+64) ----
    const int l15 = lane & 15;
    const int lg  = lane >> 4;     // k = k0 + lg*8 + j

    f32x4 acc[2][4];
    #pragma unroll
    for (int m = 0; m < 2; ++m)
        #pragma unroll
        for (int n = 0; n < 4; ++n) acc[m][n] = (f32x4){0.f, 0.f, 0.f, 0.f};

    const unsigned short* ebase =
        encT + ((size_t)b << 16) + (size_t)(wid * 64 + l15) * S_FIX + lg * 8;

    #pragma unroll 2
    for (int k0 = 0; k0 < S_FIX; k0 += 32) {
        bf16x8 bfr[4];
        #pragma unroll
        for (int n = 0; n < 4; ++n)
            bfr[n] = *(const bf16x8*)(ebase + (size_t)n * 16 * S_FIX + k0);
        bf16x8 afr[2];
        #pragma unroll
        for (int m = 0; m < 2; ++m) {
            int tl = m * 16 + l15;
            int byte = tl * 512 + ((2 * (k0 + lg * 8)) ^ ((tl & 7) << 4));
            afr[m] = *(const bf16x8*)(smem + byte);
        }
        #pragma unroll
        for (int m = 0; m < 2; ++m)
            #pragma unroll
            for (int n = 0; n < 4; ++n)
                acc[m][n] = __builtin_amdgcn_mfma_f32_16x16x32_bf16(
                    afr[m], bfr[n], acc[m][n], 0, 0, 0);
    }

    // ---- epilogue: LDS transpose (2 chunks of 16 rows) + PE + dwordx4 stores ----
    float* stg = (float*)smem;
    const float kf = -logf(10000.0f) / (float)D_FIX;
    const int dd = lane * 4;                         // 4 consecutive d per lane
    const float f0 = __expf(kf * (float)(dd));       // dd even
    const float f2 = __expf(kf * (float)(dd + 2));

    #pragma unroll
    for (int m = 0; m < 2; ++m) {
        __syncthreads();   // previous reads of smem complete before overwrite
        #pragma unroll
        for (int n = 0; n < 4; ++n) {
            const int d = wid * 64 + n * 16 + l15;
            #pragma unroll
            for (int r = 0; r < 4; ++r) {
                const int rl = lg * 4 + r;           // row-local 0..15
                stg[rl * STG_STRIDE + d] = acc[m][n][r];
            }
        }
        __syncthreads();
        #pragma unroll
        for (int i = 0; i < 4; ++i) {
            const int rl = wid * 4 + i;              // wave stores 4 full rows
            const int t  = t0 + m * 16 + rl;
            const float inv = s_winv[m * 16 + rl];
            f32x4 v = *(const f32x4*)(stg + rl * STG_STRIDE + dd);
            float sa, ca, sb, cb;
            __sincosf((float)t * f0, &sa, &ca);
            __sincosf((float)t * f2, &sb, &cb);
            v[0] = v[0] * inv + sa;
            v[1] = v[1] * inv + ca;
            v[2] = v[2] * inv + sb;
            v[3] = v[3] * inv + cb;
            *(f32x4*)(out + (size_t)b * T * D_FIX + (size_t)t * D_FIX + dd) = v;
        }
    }
}

// ---------------- fallback (round-1 f32 kernel) ----------------
#define FBM 32
__global__ __launch_bounds__(BLOCK) void gauss_up_f32(
    const float* __restrict__ enc, const float* __restrict__ dur,
    const float* __restrict__ rng, float* __restrict__ out,
    int T, int D, int ntiles)
{
    __shared__ float s_w[FBM][S_FIX];
    __shared__ float s_c[S_FIX];
    __shared__ float s_ir2[S_FIX];
    __shared__ float s_scan[S_FIX];
    __shared__ float s_part[8][FBM];
    __shared__ float s_winv[FBM];

    const int tid = threadIdx.x;
    const int b   = blockIdx.x / ntiles;
    const int t0  = (blockIdx.x % ntiles) * FBM;

    float dv = dur[b * S_FIX + tid];
    s_scan[tid] = dv;
    __syncthreads();
    #pragma unroll
    for (int off = 1; off < S_FIX; off <<= 1) {
        float cur = s_scan[tid];
        float add = (tid >= off) ? s_scan[tid - off] : 0.0f;
        __syncthreads();
        s_scan[tid] = cur + add;
        __syncthreads();
    }
    {
        float e = s_scan[tid];
        float c = e - 0.5f * dv;
        float r = rng[b * S_FIX + tid];
        s_c[tid] = c; s_ir2[tid] = 1.0f / (r * r);
    }
    __syncthreads();
    {
        float cc = s_c[tid], ir = s_ir2[tid];
        #pragma unroll 4
        for (int tl = 0; tl < FBM; ++tl) {
            float tt = (float)(t0 + tl);
            float df = tt - cc;
            s_w[tl][tid] = __expf(-ir * df * df);
        }
    }
    __syncthreads();
    {
        const int t = tid & 31, ch = tid >> 5;
        float ps = 0.0f;
        #pragma unroll 8
        for (int j = 0; j < 32; ++j) ps += s_w[t][ch * 32 + ((j + t) & 31)];
        s_part[ch][t] = ps;
    }
    __syncthreads();
    if (tid < FBM) {
        float w2 = s_part[0][tid] + s_part[1][tid] + s_part[2][tid] + s_part[3][tid]
                 + s_part[4][tid] + s_part[5][tid] + s_part[6][tid] + s_part[7][tid] + 1e-20f;
        s_winv[tid] = 1.0f / w2;
    }
    __syncthreads();

    const int dq = tid & 63, tg = tid >> 6;
    float4 acc[8];
    #pragma unroll
    for (int i = 0; i < 8; ++i) acc[i] = make_float4(0.f, 0.f, 0.f, 0.f);
    const float* encb = enc + (size_t)b * S_FIX * D + (size_t)dq * 4;
    #pragma unroll 4
    for (int s = 0; s < S_FIX; ++s) {
        float4 ev = *(const float4*)(encb + (size_t)s * D);
        #pragma unroll
        for (int i = 0; i < 8; ++i) {
            float wv = s_w[tg * 8 + i][s];
            acc[i].x = fmaf(wv, ev.x, acc[i].x);
            acc[i].y = fmaf(wv, ev.y, acc[i].y);
            acc[i].z = fmaf(wv, ev.z, acc[i].z);
            acc[i].w = fmaf(wv, ev.w, acc[i].w);
        }
    }
    const float kf = -logf(10000.0f) / (float)D;
    const int d0 = dq * 4;
    const float f0 = __expf(kf * (float)(d0));
    const float f2 = __expf(kf * (float)(d0 + 2));
    float* outb = out + (size_t)b * T * D + (size_t)t0 * D + d0;
    #pragma unroll
    for (int i = 0; i < 8; ++i) {
        const int tl = tg * 8 + i;
        const float inv = s_winv[tl];
        const float tt = (float)(t0 + tl);
        const float a0 = tt * f0, a2 = tt * f2;
        float4 o;
        o.x = acc[i].x * inv + __sinf(a0);
        o.y = acc[i].y * inv + __cosf(a0);
        o.z = acc[i].z * inv + __sinf(a2);
        o.w = acc[i].w * inv + __cosf(a2);
        *(float4*)(outb + (size_t)tl * D) = o;
    }
}

extern "C" void kernel_launch(void* const* d_in, const int* in_sizes, int n_in,
                              void* d_out, int out_size, void* d_ws, size_t ws_size,
                              hipStream_t stream) {
    const float* enc = (const float*)d_in[0];
    const float* dur = (const float*)d_in[1];
    const float* rng = (const float*)d_in[2];
    float* out = (float*)d_out;

    const int S  = S_FIX;
    const int BS = in_sizes[1];
    const int B  = BS / S;
    const int D  = in_sizes[0] / BS;
    const int T  = out_size / (B * D);

    const size_t need = (size_t)B * D * S * sizeof(unsigned short);  // 4 MB

    if (D == D_FIX && (T % BM) == 0 && ws_size >= need) {
        unsigned short* encT = (unsigned short*)d_ws;
        const int nthr = B * (S / 8) * D;
        hipLaunchKernelGGL(transpose_enc_bf16, dim3(nthr / 256), dim3(256), 0, stream,
                           enc, encT);
        hipLaunchKernelGGL(gauss_up_mfma, dim3(B * (T / BM)), dim3(BLOCK), 0, stream,
                           dur, rng, encT, out, T);
    } else {
        const int ntiles = T / FBM;
        hipLaunchKernelGGL(gauss_up_f32, dim3(B * ntiles), dim3(BLOCK), 0, stream,
                           enc, dur, rng, out, T, D, ntiles);
    }
}

// Round 4
// 48.251 us; speedup vs baseline: 2.1996x; 1.0211x over previous
//
#include <hip/hip_runtime.h>
#include <hip/hip_bf16.h>
#include <math.h>

// Gaussian upsampling, round 4: 1-wave workgroups, zero multi-wave barriers.
//   prepass : enc (B,S,D) f32 -> encT (B,D,S) bf16 in d_ws (unchanged, validated)
//   main    : grid = B x (T/32) x (D/64), 64-thread blocks (1 wave):
//     - per-wave shfl scan -> s_c / s_nir in LDS
//     - k-loop: A-fragments (w) computed IN REGISTERS (16 expf + cvt_pk per step),
//       B-fragments b128 from L2-resident encT, 8 MFMA per step, no barriers
//     - w2 = in-lane sum of bf16-rounded w + shfl_xor(16,32)  (self-consistent)
//     - epilogue: single-wave LDS transpose (stride 68) -> coalesced dwordx4
//       stores, 1/w2 + sinusoidal PE fused

typedef short  bf16x8 __attribute__((ext_vector_type(8)));
typedef float  f32x4  __attribute__((ext_vector_type(4)));
typedef int    i32x4  __attribute__((ext_vector_type(4)));
typedef unsigned short u16x8 __attribute__((ext_vector_type(8)));

#define S_FIX 256
#define D_FIX 256
#define BM 32          // t-rows per block
#define BN 64          // d-cols per block
#define STG 68         // staging stride in floats (272 B, 16B-aligned)

static __device__ __forceinline__ unsigned short f2bf(float f) {
    union { float f; unsigned u; } v; v.f = f;
    unsigned r = v.u + 0x7FFFu + ((v.u >> 16) & 1u);   // RNE
    return (unsigned short)(r >> 16);
}

// pack two f32 -> one u32 of 2x bf16 (RNE); compiler emits v_cvt_pk_bf16_f32
static __device__ __forceinline__ unsigned pack_bf2(float lo, float hi) {
    float2 v; v.x = lo; v.y = hi;
    union { __hip_bfloat162 h; unsigned u; } c;
    c.h = __float22bfloat162_rn(v);
    return c.u;   // low 16 = bf16(lo), high 16 = bf16(hi)
}

// ---------------- prepass: enc (B,S,D) f32 -> encT (B,D,S) bf16 ----------------
__global__ __launch_bounds__(256) void transpose_enc_bf16(
    const float* __restrict__ enc, unsigned short* __restrict__ encT)
{
    const int g  = blockIdx.x * 256 + threadIdx.x;
    const int d  = g & 255;
    const int sc = (g >> 8) & 31;
    const int b  = g >> 13;
    const int s0 = sc * 8;
    const float* p = enc + ((size_t)b << 16) + (size_t)s0 * D_FIX + d;
    u16x8 v;
    #pragma unroll
    for (int j = 0; j < 8; ++j) v[j] = f2bf(p[(size_t)j * D_FIX]);
    *(u16x8*)(encT + ((size_t)b << 16) + (size_t)d * S_FIX + s0) = v;
}

// ---------------- main: 1 wave per block ----------------
__global__ __launch_bounds__(64, 4) void gauss_up_mfma(
    const float* __restrict__ dur,            // (B,S)
    const float* __restrict__ rng,            // (B,S,1)
    const unsigned short* __restrict__ encT,  // (B,D,S) bf16
    float* __restrict__ out,                  // (B,T,D)
    int T)
{
    __shared__ float s_c[S_FIX];
    __shared__ float s_nir[S_FIX];            // -1/r^2
    __shared__ __align__(16) float stg[16 * STG];

    const int lane = threadIdx.x;             // 0..63
    const int l15  = lane & 15;
    const int lg   = lane >> 4;
    const int nblk = (T / BM) * (D_FIX / BN);
    const int b    = blockIdx.x / nblk;
    const int rem  = blockIdx.x % nblk;
    const int t0   = (rem / (D_FIX / BN)) * BM;
    const int d0   = (rem % (D_FIX / BN)) * BN;

    // ---- per-wave scan of durations; park c and -1/r^2 in LDS ----
    {
        f32x4 dv = *(const f32x4*)(dur + b * S_FIX + 4 * lane);
        f32x4 rg = *(const f32x4*)(rng + b * S_FIX + 4 * lane);
        float q0 = dv[0];
        float q1 = q0 + dv[1];
        float q2 = q1 + dv[2];
        float q3 = q2 + dv[3];
        float tot = q3;
        #pragma unroll
        for (int off = 1; off < 64; off <<= 1) {
            float n = __shfl_up(tot, off, 64);
            if (lane >= off) tot += n;
        }
        float excl = __shfl_up(tot, 1, 64);
        if (lane == 0) excl = 0.0f;
        f32x4 c4, n4;
        c4[0] = excl + q0 - 0.5f * dv[0];
        c4[1] = excl + q1 - 0.5f * dv[1];
        c4[2] = excl + q2 - 0.5f * dv[2];
        c4[3] = excl + q3 - 0.5f * dv[3];
        #pragma unroll
        for (int i = 0; i < 4; ++i) n4[i] = -1.0f / (rg[i] * rg[i]);
        *(f32x4*)(s_c   + 4 * lane) = c4;
        *(f32x4*)(s_nir + 4 * lane) = n4;
    }
    __syncthreads();   // single-wave barrier (cheap)

    // ---- k-loop: registers-only A, global B, 8 MFMA per step ----
    f32x4 acc[2][4];
    #pragma unroll
    for (int m = 0; m < 2; ++m)
        #pragma unroll
        for (int n = 0; n < 4; ++n) acc[m][n] = (f32x4){0.f, 0.f, 0.f, 0.f};

    float sum0 = 0.0f, sum1 = 0.0f;
    const float tt0 = (float)(t0 + l15);
    const float tt1 = (float)(t0 + 16 + l15);
    const unsigned short* eb =
        encT + ((size_t)b << 16) + (size_t)(d0 + l15) * S_FIX + lg * 8;

    #pragma unroll 2
    for (int k0 = 0; k0 < S_FIX; k0 += 32) {
        // broadcast LDS reads (16 lanes same addr -> conflict-free)
        f32x4 cA = *(const f32x4*)(s_c   + k0 + lg * 8);
        f32x4 cB = *(const f32x4*)(s_c   + k0 + lg * 8 + 4);
        f32x4 nA = *(const f32x4*)(s_nir + k0 + lg * 8);
        f32x4 nB = *(const f32x4*)(s_nir + k0 + lg * 8 + 4);

        bf16x8 bfr[4];
        #pragma unroll
        for (int n = 0; n < 4; ++n)
            bfr[n] = *(const bf16x8*)(eb + (size_t)n * 16 * S_FIX + k0);

        i32x4 a0i, a1i;
        #pragma unroll
        for (int j2 = 0; j2 < 4; ++j2) {          // k pair = (2*j2, 2*j2+1)
            const float ca_ = (j2 < 2) ? cA[(2 * j2) & 3]     : cB[(2 * j2) & 3];
            const float cb_ = (j2 < 2) ? cA[(2 * j2 + 1) & 3] : cB[(2 * j2 + 1) & 3];
            const float na_ = (j2 < 2) ? nA[(2 * j2) & 3]     : nB[(2 * j2) & 3];
            const float nb_ = (j2 < 2) ? nA[(2 * j2 + 1) & 3] : nB[(2 * j2 + 1) & 3];
            float e0a = tt0 - ca_, e0b = tt0 - cb_;
            float e1a = tt1 - ca_, e1b = tt1 - cb_;
            unsigned p0 = pack_bf2(__expf(na_ * e0a * e0a), __expf(nb_ * e0b * e0b));
            unsigned p1 = pack_bf2(__expf(na_ * e1a * e1a), __expf(nb_ * e1b * e1b));
            a0i[j2] = (int)p0;
            a1i[j2] = (int)p1;
            sum0 += __uint_as_float(p0 << 16) + __uint_as_float(p0 & 0xFFFF0000u);
            sum1 += __uint_as_float(p1 << 16) + __uint_as_float(p1 & 0xFFFF0000u);
        }
        union { i32x4 i; bf16x8 v; } ua, ub;
        ua.i = a0i; ub.i = a1i;
        #pragma unroll
        for (int n = 0; n < 4; ++n) {
            acc[0][n] = __builtin_amdgcn_mfma_f32_16x16x32_bf16(ua.v, bfr[n], acc[0][n], 0, 0, 0);
            acc[1][n] = __builtin_amdgcn_mfma_f32_16x16x32_bf16(ub.v, bfr[n], acc[1][n], 0, 0, 0);
        }
    }

    // ---- w2 over the 4 k-slice lanes (same l15, lg varies) ----
    sum0 += __shfl_xor(sum0, 16, 64);
    sum0 += __shfl_xor(sum0, 32, 64);
    sum1 += __shfl_xor(sum1, 16, 64);
    sum1 += __shfl_xor(sum1, 32, 64);
    const float inv0 = 1.0f / (sum0 + 1e-20f);   // row l15      (m=0)
    const float inv1 = 1.0f / (sum1 + 1e-20f);   // row 16+l15   (m=1)

    // ---- epilogue: single-wave LDS transpose + PE + coalesced stores ----
    const float kf  = -logf(10000.0f) / (float)D_FIX;
    const float fr0 = __expf(kf * (float)(d0 + 4 * l15));       // even col
    const float fr2 = __expf(kf * (float)(d0 + 4 * l15 + 2));
    float* ob = out + (size_t)b * T * D_FIX + (size_t)t0 * D_FIX + d0;

    #pragma unroll
    for (int m = 0; m < 2; ++m) {
        __syncthreads();
        #pragma unroll
        for (int n = 0; n < 4; ++n)
            #pragma unroll
            for (int r = 0; r < 4; ++r)
                stg[(lg * 4 + r) * STG + n * 16 + l15] = acc[m][n][r];
        __syncthreads();
        const float invm = m ? inv1 : inv0;
        #pragma unroll
        for (int i = 0; i < 4; ++i) {
            const int rr = 4 * i + lg;                    // row-local 0..15
            f32x4 v = *(const f32x4*)(stg + rr * STG + 4 * l15);
            const float iv = __shfl(invm, rr, 64);        // lane rr holds row rr
            const float t  = (float)(t0 + m * 16 + rr);
            float sa, ca2, sb, cb2;
            __sincosf(t * fr0, &sa, &ca2);
            __sincosf(t * fr2, &sb, &cb2);
            v[0] = v[0] * iv + sa;
            v[1] = v[1] * iv + ca2;
            v[2] = v[2] * iv + sb;
            v[3] = v[3] * iv + cb2;
            *(f32x4*)(ob + (size_t)(m * 16 + rr) * D_FIX + 4 * l15) = v;
        }
    }
}

// ---------------- fallback (round-1 f32 kernel, used if ws too small) ----------------
#define FBM 32
#define BLOCK 256
__global__ __launch_bounds__(BLOCK) void gauss_up_f32(
    const float* __restrict__ enc, const float* __restrict__ dur,
    const float* __restrict__ rng, float* __restrict__ out,
    int T, int D, int ntiles)
{
    __shared__ float s_w[FBM][S_FIX];
    __shared__ float s_c[S_FIX];
    __shared__ float s_ir2[S_FIX];
    __shared__ float s_scan[S_FIX];
    __shared__ float s_part[8][FBM];
    __shared__ float s_winv[FBM];

    const int tid = threadIdx.x;
    const int b   = blockIdx.x / ntiles;
    const int t0  = (blockIdx.x % ntiles) * FBM;

    float dv = dur[b * S_FIX + tid];
    s_scan[tid] = dv;
    __syncthreads();
    #pragma unroll
    for (int off = 1; off < S_FIX; off <<= 1) {
        float cur = s_scan[tid];
        float add = (tid >= off) ? s_scan[tid - off] : 0.0f;
        __syncthreads();
        s_scan[tid] = cur + add;
        __syncthreads();
    }
    {
        float e = s_scan[tid];
        float c = e - 0.5f * dv;
        float r = rng[b * S_FIX + tid];
        s_c[tid] = c; s_ir2[tid] = 1.0f / (r * r);
    }
    __syncthreads();
    {
        float cc = s_c[tid], ir = s_ir2[tid];
        #pragma unroll 4
        for (int tl = 0; tl < FBM; ++tl) {
            float tt = (float)(t0 + tl);
            float df = tt - cc;
            s_w[tl][tid] = __expf(-ir * df * df);
        }
    }
    __syncthreads();
    {
        const int t = tid & 31, ch = tid >> 5;
        float ps = 0.0f;
        #pragma unroll 8
        for (int j = 0; j < 32; ++j) ps += s_w[t][ch * 32 + ((j + t) & 31)];
        s_part[ch][t] = ps;
    }
    __syncthreads();
    if (tid < FBM) {
        float w2 = s_part[0][tid] + s_part[1][tid] + s_part[2][tid] + s_part[3][tid]
                 + s_part[4][tid] + s_part[5][tid] + s_part[6][tid] + s_part[7][tid] + 1e-20f;
        s_winv[tid] = 1.0f / w2;
    }
    __syncthreads();

    const int dq = tid & 63, tg = tid >> 6;
    float4 acc[8];
    #pragma unroll
    for (int i = 0; i < 8; ++i) acc[i] = make_float4(0.f, 0.f, 0.f, 0.f);
    const float* encb = enc + (size_t)b * S_FIX * D + (size_t)dq * 4;
    #pragma unroll 4
    for (int s = 0; s < S_FIX; ++s) {
        float4 ev = *(const float4*)(encb + (size_t)s * D);
        #pragma unroll
        for (int i = 0; i < 8; ++i) {
            float wv = s_w[tg * 8 + i][s];
            acc[i].x = fmaf(wv, ev.x, acc[i].x);
            acc[i].y = fmaf(wv, ev.y, acc[i].y);
            acc[i].z = fmaf(wv, ev.z, acc[i].z);
            acc[i].w = fmaf(wv, ev.w, acc[i].w);
        }
    }
    const float kf = -logf(10000.0f) / (float)D;
    const int d0 = dq * 4;
    const float f0 = __expf(kf * (float)(d0));
    const float f2 = __expf(kf * (float)(d0 + 2));
    float* outb = out + (size_t)b * T * D + (size_t)t0 * D + d0;
    #pragma unroll
    for (int i = 0; i < 8; ++i) {
        const int tl = tg * 8 + i;
        const float inv = s_winv[tl];
        const float tt = (float)(t0 + tl);
        const float a0 = tt * f0, a2 = tt * f2;
        float4 o;
        o.x = acc[i].x * inv + __sinf(a0);
        o.y = acc[i].y * inv + __cosf(a0);
        o.z = acc[i].z * inv + __sinf(a2);
        o.w = acc[i].w * inv + __cosf(a2);
        *(float4*)(outb + (size_t)tl * D) = o;
    }
}

extern "C" void kernel_launch(void* const* d_in, const int* in_sizes, int n_in,
                              void* d_out, int out_size, void* d_ws, size_t ws_size,
                              hipStream_t stream) {
    const float* enc = (const float*)d_in[0];
    const float* dur = (const float*)d_in[1];
    const float* rng = (const float*)d_in[2];
    float* out = (float*)d_out;

    const int S  = S_FIX;
    const int BS = in_sizes[1];
    const int B  = BS / S;
    const int D  = in_sizes[0] / BS;
    const int T  = out_size / (B * D);

    const size_t need = (size_t)B * D * S * sizeof(unsigned short);  // 4 MB

    if (D == D_FIX && (T % BM) == 0 && ws_size >= need) {
        unsigned short* encT = (unsigned short*)d_ws;
        const int nthr = B * (S / 8) * D;
        hipLaunchKernelGGL(transpose_enc_bf16, dim3(nthr / 256), dim3(256), 0, stream,
                           enc, encT);
        const int nblk = B * (T / BM) * (D_FIX / BN);   // 8192
        hipLaunchKernelGGL(gauss_up_mfma, dim3(nblk), dim3(64), 0, stream,
                           dur, rng, encT, out, T);
    } else {
        const int ntiles = T / FBM;
        hipLaunchKernelGGL(gauss_up_f32, dim3(B * ntiles), dim3(BLOCK), 0, stream,
                           enc, dur, rng, out, T, D, ntiles);
    }
}